// Round 1
// baseline (1023.706 us; speedup 1.0000x reference)
//
#include <hip/hip_runtime.h>

// NearestEmbed (VQ argmin + gather), MI355X gfx950.
// x: (B=64, D=64, H=32, W=32) fp32 ; emb: (D=64, K=512) fp32
// out0: quant (B,D,H,W) fp32 at d_out[0..4194304)
// out1: argmin (B,H,W) written as fp32 values at d_out[4194304..4259840)
//
// Structure: 4 threads per row (K split in 4 quarters of 128 codes),
// x row (64 floats) in VGPRs, emb streamed via wave-uniform loads
// (compiler should scalarize to s_load -> SGPR broadcast into v_fma),
// ||e_k||^2 precomputed per block into LDS. Butterfly shfl_xor merge.

constexpr int D  = 64;
constexpr int K  = 512;
constexpr int HW = 1024;   // 32*32

typedef float f4 __attribute__((ext_vector_type(4)));

__global__ __launch_bounds__(256, 4) void vq_argmin_kernel(
    const float* __restrict__ x,
    const float* __restrict__ emb,
    float* __restrict__ out_q,
    float* __restrict__ out_idx)
{
    __shared__ float e2s[K];

    const int tid = threadIdx.x;
    const int gt  = blockIdx.x * 256 + tid;   // global thread id
    const int r   = gt >> 2;                  // row id 0..65535
    const int q   = gt & 3;                   // K-quarter 0..3
    const int b   = r >> 10;                  // batch
    const int n   = r & 1023;                 // spatial index h*32+w

    // --- per-block ||e_k||^2 into LDS (coalesced strided reads, L2-hot) ---
    for (int k = tid; k < K; k += 256) {
        float s = 0.f;
        #pragma unroll
        for (int d = 0; d < D; ++d) {
            float v = emb[d * K + k];
            s = fmaf(v, v, s);
        }
        e2s[k] = s;
    }

    // --- load this thread's x row into registers (wave-coalesced) ---
    const float* xr = x + (size_t)(b * D) * HW + n;
    float xv[D];
    #pragma unroll
    for (int d = 0; d < D; ++d) xv[d] = xr[(size_t)d * HW];

    __syncthreads();

    // --- scan this quarter's 128 codes in groups of 16 ---
    float best = 3.4e38f;
    int   bidx = 0;
    const int kbase = q * 128;

    for (int g = 0; g < 8; ++g) {
        const int k0 = kbase + g * 16;
        float acc[16];
        #pragma unroll
        for (int i = 0; i < 16; ++i) acc[i] = 0.f;

        #pragma unroll 8
        for (int d = 0; d < D; ++d) {
            // wave-uniform address: thread-independent -> s_load + SGPR
            // operand broadcast into v_fma (no LDS, no per-lane VMEM).
            const f4* ep = (const f4*)(emb + d * K + k0);
            f4 e0 = ep[0], e1 = ep[1], e2v = ep[2], e3 = ep[3];
            float xd = xv[d];
            acc[0]  = fmaf(xd, e0.x, acc[0]);
            acc[1]  = fmaf(xd, e0.y, acc[1]);
            acc[2]  = fmaf(xd, e0.z, acc[2]);
            acc[3]  = fmaf(xd, e0.w, acc[3]);
            acc[4]  = fmaf(xd, e1.x, acc[4]);
            acc[5]  = fmaf(xd, e1.y, acc[5]);
            acc[6]  = fmaf(xd, e1.z, acc[6]);
            acc[7]  = fmaf(xd, e1.w, acc[7]);
            acc[8]  = fmaf(xd, e2v.x, acc[8]);
            acc[9]  = fmaf(xd, e2v.y, acc[9]);
            acc[10] = fmaf(xd, e2v.z, acc[10]);
            acc[11] = fmaf(xd, e2v.w, acc[11]);
            acc[12] = fmaf(xd, e3.x, acc[12]);
            acc[13] = fmaf(xd, e3.y, acc[13]);
            acc[14] = fmaf(xd, e3.z, acc[14]);
            acc[15] = fmaf(xd, e3.w, acc[15]);
        }

        #pragma unroll
        for (int i = 0; i < 16; ++i) {
            // score = -2*dot + ||e||^2 ; fmaf gives identical rounding to
            // the reference's (-2*dot) + e2 since *-2 is exact.
            float s = fmaf(-2.f, acc[i], e2s[k0 + i]);
            if (s < best) { best = s; bidx = k0 + i; }   // strict < : first-index tie-break
        }
    }

    // --- merge the 4 K-quarters (lanes q=0..3 of each row group) ---
    // Butterfly: after both steps every lane holds the row's global argmin.
    {
        float so = __shfl_xor(best, 1);
        int   io = __shfl_xor(bidx, 1);
        if (so < best || (so == best && io < bidx)) { best = so; bidx = io; }
        so = __shfl_xor(best, 2);
        io = __shfl_xor(bidx, 2);
        if (so < best || (so == best && io < bidx)) { best = so; bidx = io; }
    }

    // --- outputs: gather code vector (d-range split across the 4 lanes) ---
    float* oq = out_q + (size_t)(b * D) * HW + n;
    #pragma unroll
    for (int j = 0; j < 16; ++j) {
        int d = q * 16 + j;
        oq[(size_t)d * HW] = emb[d * K + bidx];
    }
    if (q == 0) out_idx[r] = (float)bidx;
}

extern "C" void kernel_launch(void* const* d_in, const int* in_sizes, int n_in,
                              void* d_out, int out_size, void* d_ws, size_t ws_size,
                              hipStream_t stream)
{
    const float* x   = (const float*)d_in[0];   // 64*64*32*32 = 4194304
    const float* emb = (const float*)d_in[1];   // 64*512     = 32768

    float* out_q   = (float*)d_out;             // 4194304 floats
    float* out_idx = out_q + (size_t)64 * 64 * 1024;  // 65536 floats (indices as fp32)

    // 65536 rows * 4 threads/row = 262144 threads = 1024 blocks of 256
    vq_argmin_kernel<<<1024, 256, 0, stream>>>(x, emb, out_q, out_idx);
}

// Round 2
// 166.637 us; speedup vs baseline: 6.1433x; 6.1433x over previous
//
#include <hip/hip_runtime.h>

// NearestEmbed (VQ argmin + gather), MI355X gfx950.  Round 2.
// x: (B=64, D=64, H=32, W=32) fp32 ; emb: (D=64, K=512) fp32
// out0: quant (B,D,H,W) fp32 ; out1: argmin (B,H,W) as fp32 values.
//
// Key change vs R1: emb hot-loop addresses are wave-uniform (loop counters +
// readfirstlane'd K-half), so the compiler scalarizes them to s_load /
// SGPR-broadcast feeding v_fma — no per-lane VMEM in the inner loop.
// Row<->lane mapping is contiguous so x loads and out stores are full
// 256 B/wave lines.

constexpr int D  = 64;
constexpr int K  = 512;
constexpr int HW = 1024;   // 32*32

__global__ __launch_bounds__(256, 2) void vq_argmin_kernel(
    const float* __restrict__ x,
    const float* __restrict__ emb,
    float* __restrict__ out_q,
    float* __restrict__ out_idx)
{
    __shared__ float e2s[K];
    __shared__ float mbest[128];
    __shared__ int   midx[128];

    const int tid = threadIdx.x;
    const int rl  = tid & 127;                                   // row-local 0..127
    // K-half handled by this wave: waves 0,1 -> half 0; waves 2,3 -> half 1.
    // readfirstlane makes it provably wave-uniform -> enables s_load.
    const int khalf = __builtin_amdgcn_readfirstlane(tid >> 7);
    const int r  = blockIdx.x * 128 + rl;                        // row id 0..65535
    const int b  = r >> 10;                                      // batch
    const int n  = r & 1023;                                     // h*32+w

    // --- ||e_k||^2 into LDS (lanes = consecutive k -> coalesced) ---
    for (int k = tid; k < K; k += 256) {
        float s = 0.f;
        #pragma unroll 16
        for (int d = 0; d < D; ++d) {
            float v = emb[d * K + k];
            s = fmaf(v, v, s);
        }
        e2s[k] = s;
    }

    // --- this thread's x row into VGPRs (wave lanes = consecutive n: coalesced) ---
    const float* xr = x + (size_t)(b * D) * HW + n;
    float xv[D];
    #pragma unroll
    for (int d = 0; d < D; ++d) xv[d] = xr[(size_t)d * HW];

    __syncthreads();

    // --- scan this wave's 256 codes in 16 groups of 16 ---
    float best = 3.4e38f;
    int   bidx = 0;
    const int kbase = khalf * 256;

    for (int g = 0; g < 16; ++g) {
        const int k0 = kbase + g * 16;
        float acc[16];
        #pragma unroll
        for (int i = 0; i < 16; ++i) acc[i] = 0.f;

        #pragma unroll 8
        for (int d = 0; d < D; ++d) {
            // Wave-uniform address (loop counters + SGPR kbase):
            // compiler emits s_load (SGPR broadcast), not per-lane VMEM.
            const float* ep = emb + d * K + k0;
            const float xd = xv[d];
            #pragma unroll
            for (int i = 0; i < 16; ++i)
                acc[i] = fmaf(xd, ep[i], acc[i]);
        }

        #pragma unroll
        for (int i = 0; i < 16; ++i) {
            // score = -2*dot + ||e||^2 (fp32; *-2 exact, matches reference form)
            float s = fmaf(-2.f, acc[i], e2s[k0 + i]);    // LDS broadcast read
            if (s < best) { best = s; bidx = k0 + i; }    // strict <: first-index tie-break
        }
    }

    // --- merge the two K-halves per row via LDS ---
    if (khalf == 1) { mbest[rl] = best; midx[rl] = bidx; }
    __syncthreads();

    if (khalf == 0) {
        const float ob = mbest[rl];
        const int   oi = midx[rl];
        // khalf1 indices are all >= 256 > any khalf0 index, so on exact tie
        // keep khalf0's (lower) index — matches argmin's first-min semantics.
        if (ob < best) { best = ob; bidx = oi; }

        // --- outputs: gather code vector; wave lanes = consecutive n -> full-line stores ---
        float* oq = out_q + (size_t)(b * D) * HW + n;
        #pragma unroll 8
        for (int d = 0; d < D; ++d)
            oq[(size_t)d * HW] = emb[d * K + bidx];       // L2-hot gather (emb = 128 KB)
        out_idx[r] = (float)bidx;
    }
}

extern "C" void kernel_launch(void* const* d_in, const int* in_sizes, int n_in,
                              void* d_out, int out_size, void* d_ws, size_t ws_size,
                              hipStream_t stream)
{
    const float* x   = (const float*)d_in[0];   // 4194304 floats
    const float* emb = (const float*)d_in[1];   // 32768 floats

    float* out_q   = (float*)d_out;                     // 4194304 floats
    float* out_idx = out_q + (size_t)64 * 64 * 1024;    // 65536 floats

    // 65536 rows * 2 K-halves -> 131072 threads = 512 blocks of 256
    vq_argmin_kernel<<<512, 256, 0, stream>>>(x, emb, out_q, out_idx);
}

// Round 3
// 141.361 us; speedup vs baseline: 7.2418x; 1.1788x over previous
//
#include <hip/hip_runtime.h>

// NearestEmbed (VQ argmin + gather), MI355X gfx950.  Round 3.
// x: (B=64, D=64, H=32, W=32) fp32 ; emb: (D=64, K=512) fp32
// out0: quant (B,D,H,W) fp32 ; out1: argmin (B,H,W) as fp32 values.
//
// R3 changes vs R2 (post-mortem driven):
//  * FULL unroll of every loop indexing xv[] -> x row truly in VGPRs
//    (R2's partial unroll demoted xv to scratch: VGPR_Count=32, huge stalls).
//    Group loop (8 iters) stays rolled so code = 64*16 FMAs ~ 8KB, I$-safe.
//  * 4-way K split inside a 512-thread block -> 512 blocks = 2 blocks/CU
//    = 4 waves/SIMD (was 2). Merge via LDS, slice order preserves argmin
//    first-index tie-break.
//  * Nontemporal stores for outputs (no L2 write-allocate pollution).
//  * emb stays on the scalar path: wave-uniform address -> s_load ->
//    SGPR broadcast operand in v_fma (0 per-lane traffic in hot loop).

constexpr int D  = 64;
constexpr int K  = 512;
constexpr int HW = 1024;   // 32*32

__global__ __launch_bounds__(512, 4) void vq_argmin_kernel(
    const float* __restrict__ x,
    const float* __restrict__ emb,
    float* __restrict__ out_q,
    float* __restrict__ out_idx)
{
    __shared__ float e2s[K];
    __shared__ float mb[3][128];
    __shared__ int   mi[3][128];
    __shared__ int   kfin[128];

    const int tid   = threadIdx.x;
    const int rl    = tid & 127;                                  // row-local 0..127
    const int slice = __builtin_amdgcn_readfirstlane(tid >> 7);   // wave-uniform 0..3
    const int r     = blockIdx.x * 128 + rl;                      // row id
    const int b     = r >> 10;                                    // batch
    const int n     = r & 1023;                                   // h*32+w

    // --- ||e_k||^2: one k per thread (512 threads = 512 codes), coalesced,
    //     also warms L2 with the whole emb table for the scalar loads below.
    {
        float s = 0.f;
        #pragma unroll 16
        for (int d = 0; d < D; ++d) {
            float v = emb[d * K + tid];
            s = fmaf(v, v, s);
        }
        e2s[tid] = s;
    }

    // --- x row into VGPRs. FULL unroll => compile-time indices => registers.
    const float* xr = x + (size_t)(b * D) * HW + n;
    float xv[D];
    #pragma unroll
    for (int d = 0; d < D; ++d) xv[d] = xr[(size_t)d * HW];

    __syncthreads();

    // --- scan this slice's 128 codes, 8 groups of 16 ---
    float best = 3.4e38f;
    int   bidx = 0;
    const int kbase = slice * 128;

    for (int g = 0; g < 8; ++g) {               // rolled: keeps code ~8KB
        const int k0 = kbase + g * 16;
        const float* ep = emb + k0;             // + d*K per step, wave-uniform
        float acc[16];
        #pragma unroll
        for (int i = 0; i < 16; ++i) acc[i] = 0.f;

        #pragma unroll                           // FULL: xv[d] const-indexed
        for (int d = 0; d < D; ++d) {
            const float xd = xv[d];
            #pragma unroll
            for (int i = 0; i < 16; ++i)
                acc[i] = fmaf(xd, ep[d * K + i], acc[i]);   // s_load + SGPR bcast
        }

        #pragma unroll
        for (int i = 0; i < 16; ++i) {
            float s = fmaf(-2.f, acc[i], e2s[k0 + i]);
            if (s < best) { best = s; bidx = k0 + i; }      // strict <: first-index
        }
    }

    // --- 4-way slice merge per row (slice order => lowest index wins ties) ---
    if (slice > 0) { mb[slice - 1][rl] = best; mi[slice - 1][rl] = bidx; }
    __syncthreads();

    if (tid < 128) {
        #pragma unroll
        for (int s = 0; s < 3; ++s) {
            float ob = mb[s][tid];
            int   oi = mi[s][tid];
            if (ob < best) { best = ob; bidx = oi; }
        }
        kfin[tid] = bidx;
        __builtin_nontemporal_store((float)bidx, &out_idx[blockIdx.x * 128 + tid]);
    }
    __syncthreads();

    // --- epilogue: all 512 threads gather+store (16 d-planes per thread) ---
    const int kq = kfin[rl];                     // LDS read
    float* oq = out_q + (size_t)(b * D) * HW + n;
    #pragma unroll
    for (int j = 0; j < 16; ++j) {
        int d = slice * 16 + j;
        // emb gather is per-lane (scattered 4B) but emb is L1/L2-hot (128KB);
        // stores: lanes = consecutive n -> full 256B lines, nontemporal.
        __builtin_nontemporal_store(emb[d * K + kq], &oq[(size_t)d * HW]);
    }
}

extern "C" void kernel_launch(void* const* d_in, const int* in_sizes, int n_in,
                              void* d_out, int out_size, void* d_ws, size_t ws_size,
                              hipStream_t stream)
{
    const float* x   = (const float*)d_in[0];   // 4194304 floats
    const float* emb = (const float*)d_in[1];   // 32768 floats

    float* out_q   = (float*)d_out;                     // 4194304 floats
    float* out_idx = out_q + (size_t)64 * 64 * 1024;    // 65536 floats

    // 65536 rows / 128 rows-per-block = 512 blocks of 512 threads
    // (4 K-slices per row inside the block) -> 2 blocks/CU, 4 waves/SIMD.
    vq_argmin_kernel<<<512, 512, 0, stream>>>(x, emb, out_q, out_idx);
}